// Round 1
// baseline (437.348 us; speedup 1.0000x reference)
//
#include <hip/hip_runtime.h>
#include <math.h>

// Problem constants
#define BB   2
#define CIN  32
#define COUT 32
#define DM   40
#define NE   3
#define PD   42                 // padded spatial dim
#define PLANE (PD*PD)           // 1764
#define XPAD_PER_I (PD*PLANE)   // 74088
#define NPTS (DM*DM)            // 1600
#define NVOL (DM*DM*DM)         // 64000
#define EPSBN 1e-5f

// Workspace layout (float offsets)
#define WS_WCOMB 0                        // 2*32*32*27 = 55296
#define WS_BCOMB 55296                    // 64
#define WS_SUM   55360                    // 32 (sum) + 32 (sumsq) = 64
#define WS_SCALE 55424                    // 32
#define WS_SHIFT 55456                    // 32
#define WS_XPAD  55488                    // 2*32*42^3 = 4,741,632
#define WS_Y     (55488 + 4741632)        // 2*32*40^3 = 8,192,000
// total = 12,989,120 floats = ~52 MB

// ---------------------------------------------------------------------------
// Kernel A: routing + combined weights/bias, zero stat accumulators
// ---------------------------------------------------------------------------
__global__ void prep_kernel(const float* __restrict__ emb,
                            const float* __restrict__ rw,
                            const float* __restrict__ rb,
                            const float* __restrict__ ek,
                            const float* __restrict__ ebias,
                            float* __restrict__ ws) {
    int idx = blockIdx.x * blockDim.x + threadIdx.x;
    if (idx < 64) ws[WS_SUM + idx] = 0.0f;  // zero sum[32] + sumsq[32]

    if (idx < BB * COUT * CIN * 27) {
        int b = idx / (COUT * CIN * 27);
        int rest = idx - b * (COUT * CIN * 27);
        float e0 = emb[b];  // EMB == 1
        float w = 0.0f;
        #pragma unroll
        for (int e = 0; e < NE; ++e) {
            float t = e0 * rw[e] + rb[e];
            float r = 1.0f / (1.0f + expf(-t));
            w += r * ek[e * (COUT * CIN * 27) + rest];
        }
        ws[WS_WCOMB + idx] = w;
    } else if (idx < BB * COUT * CIN * 27 + BB * COUT) {
        int j = idx - BB * COUT * CIN * 27;
        int b = j / COUT, o = j % COUT;
        float e0 = emb[b];
        float bv = 0.0f;
        #pragma unroll
        for (int e = 0; e < NE; ++e) {
            float t = e0 * rw[e] + rb[e];
            float r = 1.0f / (1.0f + expf(-t));
            bv += r * ebias[e * COUT + o];
        }
        ws[WS_BCOMB + j] = bv;
    }
}

// ---------------------------------------------------------------------------
// Kernel B: zero-pad x into [B][CIN][42][42][42]
// ---------------------------------------------------------------------------
__global__ void pad_kernel(const float* __restrict__ x, float* __restrict__ xpad) {
    int idx = blockIdx.x * blockDim.x + threadIdx.x;
    const int n = BB * CIN * XPAD_PER_I;
    if (idx >= n) return;
    int px = idx % PD;
    int py = (idx / PD) % PD;
    int pz = (idx / PLANE) % PD;
    int ci = idx / XPAD_PER_I;   // b*CIN + i
    float v = 0.0f;
    if (px >= 1 && px <= DM && py >= 1 && py <= DM && pz >= 1 && pz <= DM) {
        v = x[((ci * DM + (pz - 1)) * DM + (py - 1)) * DM + (px - 1)];
    }
    xpad[idx] = v;
}

// ---------------------------------------------------------------------------
// Kernel C: conv3d (SAME) with sliding-z window + fused batch stats
// grid: (zchunk=4, o=32, b=2), block: 512
// ---------------------------------------------------------------------------
__global__ __launch_bounds__(512) void conv_kernel(
        const float* __restrict__ wcomb,
        const float* __restrict__ bcomb,
        const float* __restrict__ xpad,
        float* __restrict__ yout,
        float* __restrict__ sums) {
    const int zc  = blockIdx.x;     // 0..3 -> z0 = zc*10
    const int o   = blockIdx.y;
    const int b   = blockIdx.z;
    const int z0  = zc * 10;
    const int tid = threadIdx.x;

    const float* wbo  = wcomb + (b * COUT + o) * CIN * 27;  // uniform -> s_load path
    const float  bias = bcomb[b * COUT + o];

    float lsum = 0.0f, lsq = 0.0f;

    for (int p = tid; p < NPTS; p += 512) {
        const int y = p / DM, x = p % DM;
        float aA = 0.0f, aB = 0.0f, aC = 0.0f;
        const float* xb0 = xpad + (b * CIN) * XPAD_PER_I + z0 * PLANE + y * PD + x;

        for (int zi = 0; zi < 12; ++zi) {
            float s0 = 0.0f, s1 = 0.0f, s2 = 0.0f;
            const float* xb = xb0 + zi * PLANE;
            const float* wp = wbo;
            for (int i = 0; i < CIN; ++i) {
                float v[9];
                #pragma unroll
                for (int t = 0; t < 3; ++t) {
                    v[3*t+0] = xb[t * PD + 0];
                    v[3*t+1] = xb[t * PD + 1];
                    v[3*t+2] = xb[t * PD + 2];
                }
                #pragma unroll
                for (int t = 0; t < 9; ++t) {
                    s0 = fmaf(wp[t],      v[t], s0);
                    s1 = fmaf(wp[9 + t],  v[t], s1);
                    s2 = fmaf(wp[18 + t], v[t], s2);
                }
                xb += XPAD_PER_I;
                wp += 27;
            }
            // plane zp = z0+zi contributes: s0->out[zp], s1->out[zp-1], s2->out[zp-2]
            aC += s0; aB += s1; aA += s2;
            if (zi >= 2) {
                const int z = z0 + zi - 2;   // in [z0, z0+10)
                float val = aA + bias;
                yout[((b * COUT + o) * DM + z) * NPTS + p] = val;
                lsum += val;
                lsq  += val * val;
            }
            aA = aB; aB = aC; aC = 0.0f;
        }
    }

    __shared__ float r1[512];
    __shared__ float r2[512];
    r1[tid] = lsum; r2[tid] = lsq;
    __syncthreads();
    for (int s = 256; s > 0; s >>= 1) {
        if (tid < s) { r1[tid] += r1[tid + s]; r2[tid] += r2[tid + s]; }
        __syncthreads();
    }
    if (tid == 0) {
        atomicAdd(&sums[o],       r1[0]);
        atomicAdd(&sums[32 + o],  r2[0]);
    }
}

// ---------------------------------------------------------------------------
// Kernel D: per-channel BN scale/shift
// ---------------------------------------------------------------------------
__global__ void bnparams_kernel(const float* __restrict__ sums,
                                const float* __restrict__ gamma,
                                const float* __restrict__ beta,
                                float* __restrict__ sc,
                                float* __restrict__ sh) {
    int c = threadIdx.x;
    if (c < COUT) {
        const float invN = 1.0f / (float)(BB * NVOL);
        float mean  = sums[c] * invN;
        float var   = sums[32 + c] * invN - mean * mean;
        float scale = gamma[c] * rsqrtf(var + EPSBN);
        sc[c] = scale;
        sh[c] = beta[c] - mean * scale;
    }
}

// ---------------------------------------------------------------------------
// Kernel E: BN apply + LeakyReLU + nearest-upsample x2 (1 thread/src voxel)
// ---------------------------------------------------------------------------
__global__ void upsample_kernel(const float* __restrict__ yin,
                                const float* __restrict__ sc,
                                const float* __restrict__ sh,
                                float* __restrict__ out) {
    int idx = blockIdx.x * blockDim.x + threadIdx.x;
    if (idx >= BB * COUT * NVOL) return;
    int x = idx % DM;
    int y = (idx / DM) % DM;
    int z = (idx / NPTS) % DM;
    int c = (idx / NVOL) % COUT;
    int cc = idx / NVOL;           // b*COUT + c

    float v = yin[idx];
    v = v * sc[c] + sh[c];
    v = (v >= 0.0f) ? v : 0.1f * v;

    float2 vv = make_float2(v, v);
    size_t obase = ((size_t)cc * 80 + (size_t)(2 * z)) * 6400
                 + (size_t)(2 * y) * 80 + (size_t)(2 * x);
    *(float2*)(out + obase)            = vv;
    *(float2*)(out + obase + 80)       = vv;
    *(float2*)(out + obase + 6400)     = vv;
    *(float2*)(out + obase + 6480)     = vv;
}

// ---------------------------------------------------------------------------
extern "C" void kernel_launch(void* const* d_in, const int* in_sizes, int n_in,
                              void* d_out, int out_size, void* d_ws, size_t ws_size,
                              hipStream_t stream) {
    const float* x     = (const float*)d_in[0];
    const float* emb   = (const float*)d_in[1];
    const float* rw    = (const float*)d_in[2];
    const float* rb    = (const float*)d_in[3];
    const float* ek    = (const float*)d_in[4];
    const float* ebias = (const float*)d_in[5];
    const float* gamma = (const float*)d_in[6];
    const float* beta  = (const float*)d_in[7];
    float* ws  = (float*)d_ws;
    float* out = (float*)d_out;

    // A: routing + combined weights/bias + zero stats
    prep_kernel<<<(BB*COUT*CIN*27 + BB*COUT + 255) / 256, 256, 0, stream>>>(
        emb, rw, rb, ek, ebias, ws);

    // B: zero-pad x
    pad_kernel<<<(BB*CIN*XPAD_PER_I + 255) / 256, 256, 0, stream>>>(
        x, ws + WS_XPAD);

    // C: conv + stats
    dim3 cgrid(4, COUT, BB);
    conv_kernel<<<cgrid, 512, 0, stream>>>(
        ws + WS_WCOMB, ws + WS_BCOMB, ws + WS_XPAD, ws + WS_Y, ws + WS_SUM);

    // D: BN params
    bnparams_kernel<<<1, 64, 0, stream>>>(
        ws + WS_SUM, gamma, beta, ws + WS_SCALE, ws + WS_SHIFT);

    // E: BN apply + LeakyReLU + upsample
    upsample_kernel<<<(BB*COUT*NVOL + 255) / 256, 256, 0, stream>>>(
        ws + WS_Y, ws + WS_SCALE, ws + WS_SHIFT, out);
}

// Round 2
// 215.843 us; speedup vs baseline: 2.0262x; 2.0262x over previous
//
#include <hip/hip_runtime.h>
#include <hip/hip_bf16.h>
#include <math.h>

// Problem constants
#define BB   2
#define CIN  32
#define COUT 32
#define DM   40
#define PD   42                 // padded spatial dim
#define NPTS (DM*DM)            // 1600
#define NVOL (DM*DM*DM)         // 64000
#define EPSBN 1e-5f
#define NBLK_CONV 4000          // 50 mchunks * 40 z * 2 b

typedef short  bf16x8  __attribute__((ext_vector_type(8)));
typedef float  floatx4 __attribute__((ext_vector_type(4)));

// Workspace layout (float offsets), all 16B-aligned
#define WS_WFRAG 0              // bf16[2*2*27*64*8 = 55296] = 27648 floats
#define WS_BCOMB 27648          // 64 floats
#define WS_SC    27712          // 32
#define WS_SH    27744          // 32
#define WS_PART  27776          // 64 * 4000 = 256000 floats  [stat][block]
#define WS_XPAD2 283776         // bf16[2*42^3*32 = 4741632] = 2370816 floats
#define WS_Y     2654592        // 2*32*64000 = 4096000 floats
// total ~6.75M floats = 27 MB

// ---------------------------------------------------------------------------
// Kernel A: routing + weights in B-fragment order (bf16) + combined bias
// wfrag[b][ntile][tap][lane][j] = W_b[i=(lane>>4)*8+j][o=ntile*16+(lane&15)][tap]
// ---------------------------------------------------------------------------
__global__ void prep_kernel(const float* __restrict__ emb,
                            const float* __restrict__ rw,
                            const float* __restrict__ rb,
                            const float* __restrict__ ek,
                            const float* __restrict__ ebias,
                            float* __restrict__ ws) {
    int idx = blockIdx.x * 256 + threadIdx.x;
    __hip_bfloat16* wfrag = (__hip_bfloat16*)(ws + WS_WFRAG);
    const int NW = 2 * 2 * 27 * 64 * 8;   // 55296
    if (idx < NW) {
        int j    = idx & 7;
        int lane = (idx >> 3) & 63;
        int tap  = (idx >> 9) % 27;
        int nt   = (idx / (27 * 512)) & 1;
        int b    = idx / (2 * 27 * 512);
        int o = nt * 16 + (lane & 15);
        int i = (lane >> 4) * 8 + j;
        float e0 = emb[b];
        float w = 0.0f;
        #pragma unroll
        for (int e = 0; e < 3; ++e) {
            float r = 1.0f / (1.0f + expf(-(e0 * rw[e] + rb[e])));
            w += r * ek[((e * COUT + o) * CIN + i) * 27 + tap];
        }
        wfrag[idx] = __float2bfloat16(w);
    } else if (idx < NW + 64) {
        int j2 = idx - NW;
        int b = j2 >> 5, o = j2 & 31;
        float e0 = emb[b];
        float bv = 0.0f;
        #pragma unroll
        for (int e = 0; e < 3; ++e) {
            float r = 1.0f / (1.0f + expf(-(e0 * rw[e] + rb[e])));
            bv += r * ebias[e * COUT + o];
        }
        ws[WS_BCOMB + j2] = bv;
    }
}

// ---------------------------------------------------------------------------
// Kernel B: repack x to channels-last, zero-padded bf16: xpad2[b][zp][yp][xp][i]
// grid (yp=42, zp=42, b=2), block 256
// ---------------------------------------------------------------------------
__global__ void repack_kernel(const float* __restrict__ x,
                              __hip_bfloat16* __restrict__ xp2) {
    int yp = blockIdx.x, zp = blockIdx.y, b = blockIdx.z;
    __hip_bfloat16* row = xp2 + ((((size_t)b * PD + zp) * PD + yp) * PD) * 32;
    bool inz = (zp >= 1 && zp <= DM && yp >= 1 && yp <= DM);
    for (int idx = threadIdx.x; idx < PD * 32; idx += 256) {
        int i = idx & 31, xp = idx >> 5;
        float v = 0.0f;
        if (inz && xp >= 1 && xp <= DM)
            v = x[(size_t)(b * CIN + i) * NVOL + (zp - 1) * NPTS + (yp - 1) * DM + (xp - 1)];
        row[idx] = __float2bfloat16(v);
    }
}

// ---------------------------------------------------------------------------
// Kernel C: implicit-GEMM conv via MFMA bf16 + fused batch-stat partials
// grid (mc=50, z=40, b=2), block 256 = 4 waves
// wave w: mtile = w&1 (16 spatial pts), ntile = w>>1 (16 out chans)
// ---------------------------------------------------------------------------
__global__ __launch_bounds__(256, 2) void conv_mfma_kernel(
        const __hip_bfloat16* __restrict__ xp2,
        const bf16x8* __restrict__ wfrag,
        const float* __restrict__ bcomb,
        float* __restrict__ y,
        float* __restrict__ part) {
    const int mc = blockIdx.x, z = blockIdx.y, b = blockIdx.z;
    const int tid = threadIdx.x, lane = tid & 63, wv = tid >> 6;
    const int mt = wv & 1, nt = wv >> 1;
    const int quad = lane >> 4, l15 = lane & 15;

    __shared__ float lstat[64];
    if (tid < 64) lstat[tid] = 0.0f;
    __syncthreads();

    // A fragment base: lane's spatial point = row of A; quad selects ch-group
    const int pa = mc * 32 + mt * 16 + l15;     // 0..1599 within plane z
    const int ya = pa / DM, xa = pa % DM;
    const char* abase = (const char*)xp2 +
        ((((size_t)b * PD + z) * PD + ya) * PD + xa) * 64 + quad * 16;
    // B fragments: pre-shuffled, lane-indexed
    const bf16x8* wbase = wfrag + ((b * 2 + nt) * 27) * 64 + lane;

    floatx4 acc0 = {0.f, 0.f, 0.f, 0.f};
    floatx4 acc1 = {0.f, 0.f, 0.f, 0.f};
    #pragma unroll
    for (int t = 0; t < 27; ++t) {
        const int dz = t / 9, dy = (t / 3) % 3, dx = t % 3;
        bf16x8 av = *(const bf16x8*)(abase + ((dz * PD + dy) * PD + dx) * 64);
        bf16x8 bv = wbase[t * 64];
        if (t & 1) acc1 = __builtin_amdgcn_mfma_f32_16x16x32_bf16(av, bv, acc1, 0, 0, 0);
        else       acc0 = __builtin_amdgcn_mfma_f32_16x16x32_bf16(av, bv, acc0, 0, 0, 0);
    }
    floatx4 acc = acc0 + acc1;

    // Epilogue: D[m=quad*4+reg][n=lane&15]; lane's 4 values share channel o
    const int o = nt * 16 + l15;
    const float bias = bcomb[b * COUT + o];
    const int po = mc * 32 + mt * 16 + quad * 4;
    float v0 = acc[0] + bias;
    float v1 = acc[1] + bias;
    float v2 = acc[2] + bias;
    float v3 = acc[3] + bias;
    float vs = v0 + v1 + v2 + v3;
    float vq = v0 * v0 + v1 * v1 + v2 * v2 + v3 * v3;
    atomicAdd(&lstat[o],      vs);
    atomicAdd(&lstat[32 + o], vq);
    *(float4*)(y + ((size_t)(b * COUT + o) * DM + z) * NPTS + po) =
        make_float4(v0, v1, v2, v3);

    __syncthreads();
    if (tid < 64) {
        int blin = (b * DM + z) * 50 + mc;      // 0..3999
        part[tid * NBLK_CONV + blin] = lstat[tid];
    }
}

// ---------------------------------------------------------------------------
// Kernel D: reduce partials -> BN scale/shift. grid 32 blocks (one per channel)
// ---------------------------------------------------------------------------
__global__ void finalize_kernel(const float* __restrict__ part,
                                const float* __restrict__ gamma,
                                const float* __restrict__ beta,
                                float* __restrict__ sc,
                                float* __restrict__ sh) {
    int c = blockIdx.x, tid = threadIdx.x;
    float s1 = 0.f, s2 = 0.f;
    for (int k = tid; k < NBLK_CONV; k += 256) {
        s1 += part[c * NBLK_CONV + k];
        s2 += part[(32 + c) * NBLK_CONV + k];
    }
    __shared__ float r1[256], r2[256];
    r1[tid] = s1; r2[tid] = s2;
    __syncthreads();
    for (int s = 128; s > 0; s >>= 1) {
        if (tid < s) { r1[tid] += r1[tid + s]; r2[tid] += r2[tid + s]; }
        __syncthreads();
    }
    if (tid == 0) {
        const float invN = 1.0f / (float)(BB * NVOL);
        float mean = r1[0] * invN;
        float var  = r2[0] * invN - mean * mean;
        float scale = gamma[c] * rsqrtf(var + EPSBN);
        sc[c] = scale;
        sh[c] = beta[c] - mean * scale;
    }
}

// ---------------------------------------------------------------------------
// Kernel E: BN apply + LeakyReLU + nearest-upsample x2 (1 thread/src voxel)
// ---------------------------------------------------------------------------
__global__ void upsample_kernel(const float* __restrict__ yin,
                                const float* __restrict__ sc,
                                const float* __restrict__ sh,
                                float* __restrict__ out) {
    int idx = blockIdx.x * blockDim.x + threadIdx.x;
    if (idx >= BB * COUT * NVOL) return;
    int x = idx % DM;
    int y = (idx / DM) % DM;
    int z = (idx / NPTS) % DM;
    int c = (idx / NVOL) % COUT;
    int cc = idx / NVOL;           // b*COUT + c

    float v = yin[idx];
    v = v * sc[c] + sh[c];
    v = (v >= 0.0f) ? v : 0.1f * v;

    float2 vv = make_float2(v, v);
    size_t obase = ((size_t)cc * 80 + (size_t)(2 * z)) * 6400
                 + (size_t)(2 * y) * 80 + (size_t)(2 * x);
    *(float2*)(out + obase)            = vv;
    *(float2*)(out + obase + 80)       = vv;
    *(float2*)(out + obase + 6400)     = vv;
    *(float2*)(out + obase + 6480)     = vv;
}

// ---------------------------------------------------------------------------
extern "C" void kernel_launch(void* const* d_in, const int* in_sizes, int n_in,
                              void* d_out, int out_size, void* d_ws, size_t ws_size,
                              hipStream_t stream) {
    const float* x     = (const float*)d_in[0];
    const float* emb   = (const float*)d_in[1];
    const float* rw    = (const float*)d_in[2];
    const float* rb    = (const float*)d_in[3];
    const float* ek    = (const float*)d_in[4];
    const float* ebias = (const float*)d_in[5];
    const float* gamma = (const float*)d_in[6];
    const float* beta  = (const float*)d_in[7];
    float* ws  = (float*)d_ws;
    float* out = (float*)d_out;

    __hip_bfloat16* xp2 = (__hip_bfloat16*)(ws + WS_XPAD2);

    // A: routing + B-fragment weights + bias
    prep_kernel<<<(55296 + 64 + 255) / 256, 256, 0, stream>>>(emb, rw, rb, ek, ebias, ws);

    // B: channels-last zero-padded bf16 repack
    repack_kernel<<<dim3(PD, PD, BB), 256, 0, stream>>>(x, xp2);

    // C: MFMA conv + stat partials
    conv_mfma_kernel<<<dim3(50, DM, BB), 256, 0, stream>>>(
        xp2, (const bf16x8*)(ws + WS_WFRAG), ws + WS_BCOMB, ws + WS_Y, ws + WS_PART);

    // D: BN params
    finalize_kernel<<<32, 256, 0, stream>>>(ws + WS_PART, gamma, beta,
                                            ws + WS_SC, ws + WS_SH);

    // E: BN apply + LeakyReLU + upsample
    upsample_kernel<<<(BB * COUT * NVOL + 255) / 256, 256, 0, stream>>>(
        ws + WS_Y, ws + WS_SC, ws + WS_SH, out);
}